// Round 18
// baseline (22451.389 us; speedup 1.0000x reference)
//
#include <hip/hip_runtime.h>
#include <math.h>

#define TT 256
#define BB 32
#define DD 512
#define HH 512
#define H3 1536

static constexpr size_t SZ_I2HT = 3ull * H3 * HH;
static constexpr size_t SZ_H2HT = 3ull * H3 * HH;
static constexpr size_t SZ_WCT  = 3ull * HH * HH;
static constexpr size_t SZ_WGT  = 9ull * HH * HH;
static constexpr size_t SZ_UGT  = 9ull * HH * H3;
static constexpr size_t SZ_UCT  = 9ull * HH * HH;
static constexpr size_t SZ_ST   = 3ull * BB * HH;
static constexpr size_t SZ_GH   = 3ull * BB * H3;
static constexpr size_t SZ_UGP  = 3ull * 9 * BB * HH;  // partials [chunk][q][b][col]
static constexpr size_t SZ_UCB  = 9ull * BB * HH;

static constexpr size_t OFF_I2HT = 0;
static constexpr size_t OFF_H2HT = OFF_I2HT + SZ_I2HT;
static constexpr size_t OFF_WCT  = OFF_H2HT + SZ_H2HT;
static constexpr size_t OFF_WGT  = OFF_WCT + SZ_WCT;
static constexpr size_t OFF_UGT  = OFF_WGT + SZ_WGT;
static constexpr size_t OFF_UCT  = OFF_UGT + SZ_UGT;
static constexpr size_t OFF_HST  = OFF_UCT + SZ_UCT;
static constexpr size_t OFF_CST  = OFF_HST + SZ_ST;
static constexpr size_t OFF_GH   = OFF_CST + SZ_ST;
static constexpr size_t OFF_UGP  = OFF_GH + SZ_GH;
static constexpr size_t OFF_UCB  = OFF_UGP + SZ_UGP;
static constexpr size_t WS_FLOATS = OFF_UCB + SZ_UCB;

struct KArgs {
  const float* x;
  const float *b_i2h, *b_h2h, *b_wg, *b_ug, *b_uc, *b_wc;
  const float *i2hT, *h2hT, *wcT, *wgT, *ugT, *ucT;
  float *hst, *cst, *gh, *ugp, *ucb, *out;
};

// ---------------- cross-XCD coherent access helpers (sc1 path, no cache flushes)
__device__ __forceinline__ float cload(const float* p) {
  return __hip_atomic_load(p, __ATOMIC_RELAXED, __HIP_MEMORY_SCOPE_AGENT);
}
__device__ __forceinline__ void cstore(float* p, float v) {
  __hip_atomic_store(p, v, __ATOMIC_RELAXED, __HIP_MEMORY_SCOPE_AGENT);
}
__device__ __forceinline__ void cstore2(float* p, float2 v) {
  __hip_atomic_store(reinterpret_cast<unsigned long long*>(p),
                     __builtin_bit_cast(unsigned long long, v),
                     __ATOMIC_RELAXED, __HIP_MEMORY_SCOPE_AGENT);
}

// ---------------- barrier: 64-sharded arrivals + wave-parallel poll (r13/r15)
__device__ unsigned int g_cnt[64 * 64];   // counters at g_cnt[i*64], 256B apart

__global__ void k_zero() {
  for (int i = threadIdx.x; i < 64 * 64; i += blockDim.x) g_cnt[i] = 0u;
}

__device__ __forceinline__ void poll_until(unsigned int target) {
  if (threadIdx.x < 64) {
    for (;;) {
      unsigned int s = __hip_atomic_load(&g_cnt[threadIdx.x * 64],
                                         __ATOMIC_RELAXED, __HIP_MEMORY_SCOPE_AGENT);
      s += __shfl_xor(s, 1);
      s += __shfl_xor(s, 2);
      s += __shfl_xor(s, 4);
      s += __shfl_xor(s, 8);
      s += __shfl_xor(s, 16);
      s += __shfl_xor(s, 32);
      if (s >= target) break;
      __builtin_amdgcn_s_sleep(8);
    }
  }
}

__device__ __forceinline__ void gbar_arrive(unsigned int target) {
  __syncthreads();
  if (threadIdx.x == 0) {
    __hip_atomic_fetch_add(&g_cnt[(blockIdx.x & 63) * 64], 1u,
                           __ATOMIC_RELAXED, __HIP_MEMORY_SCOPE_AGENT);
  }
  poll_until(target);
  __syncthreads();
}

__device__ __forceinline__ void gbar_wait(unsigned int target) {
  __syncthreads();
  poll_until(target);
  __syncthreads();
}

// ---------------- transpose: in [K][N] -> out [N][K], grid (N/32, K/32, nmat)
__global__ __launch_bounds__(256) void k_transpose(const float* __restrict__ in,
                                                   float* __restrict__ out,
                                                   int K, int N) {
  __shared__ float t[32][33];
  size_t mo = (size_t)blockIdx.z * K * N;
  in += mo; out += mo;
  int n0 = blockIdx.x * 32, k0 = blockIdx.y * 32;
  int c = threadIdx.x & 31, r0 = (threadIdx.x >> 5) * 4;
#pragma unroll
  for (int i = 0; i < 4; ++i) t[r0 + i][c] = in[(size_t)(k0 + r0 + i) * N + n0 + c];
  __syncthreads();
#pragma unroll
  for (int i = 0; i < 4; ++i) out[(size_t)(n0 + r0 + i) * K + k0 + c] = t[c][r0 + i];
}

__global__ void k_copy(const float* __restrict__ a, float* __restrict__ o, int n) {
  int i = blockIdx.x * blockDim.x + threadIdx.x;
  if (i < n) o[i] = a[i];
}

// k-aware XOR swizzle: granule g (16B) of a row stored at slot g^((g>>4)&7).
__device__ __forceinline__ int xslot(int g) { return g ^ ((g >> 4) & 7); }

// 8-row x stage for phase B l==0 (16 KB)
__device__ __forceinline__ void stage_rows8(const float* __restrict__ src,
                                            float* __restrict__ sx, int tid, int row0) {
#pragma unroll
  for (int i = 0; i < 4; ++i) {
    int fi = tid + i * 256;
    int b = row0 + (fi >> 7), g = fi & 127;
    float4 v = reinterpret_cast<const float4*>(src)[(size_t)b * 128 + g];
    *reinterpret_cast<float4*>(&sx[b * HH + (xslot(g) << 2)]) = v;
  }
}

// 8-row coherent 16B sc1 stage for phase B l>0 (r14/r17)
__device__ __forceinline__ void stage_rows8_coh(const float* __restrict__ src,
                                                float* __restrict__ sx, int tid, int row0) {
  float4 v[4];
#pragma unroll
  for (int i = 0; i < 4; ++i) {
    int fi = tid + i * 256;
    int b = row0 + (fi >> 7), g = fi & 127;
    const float* p = src + (size_t)b * HH + g * 4;
    asm volatile("global_load_dwordx4 %0, %1, off sc1" : "=v"(v[i]) : "v"(p));
  }
  asm volatile("s_waitcnt vmcnt(0)" ::: "memory");
#pragma unroll
  for (int i = 0; i < 4; ++i) {
    int fi = tid + i * 256;
    int b = row0 + (fi >> 7), g = fi & 127;
    *reinterpret_cast<float4*>(&sx[b * HH + (xslot(g) << 2)]) = v[i];
  }
}

// 16-row parity-half stage for phase A (32 KB; r14/r15)
__device__ __forceinline__ void stage_half_coh(const float* __restrict__ src,
                                               float* __restrict__ sx, int tid) {
  float4 v[8];
#pragma unroll
  for (int i = 0; i < 8; ++i) {
    int fi = tid + i * 256;
    const float* p = src + (size_t)fi * 4;
    asm volatile("global_load_dwordx4 %0, %1, off sc1" : "=v"(v[i]) : "v"(p));
  }
  asm volatile("s_waitcnt vmcnt(0)" ::: "memory");
#pragma unroll
  for (int i = 0; i < 8; ++i) {
    int fi = tid + i * 256;
    int b = fi >> 7, g = fi & 127;
    *reinterpret_cast<float4*>(&sx[b * HH + (xslot(g) << 2)]) = v[i];
  }
}

__device__ __forceinline__ float dot4(float4 x, float4 w) {
  return x.x * w.x + x.y * w.y + x.z * w.z + x.w * w.w;
}

__device__ __forceinline__ float sigm(float x) { return 1.0f / (1.0f + expf(-x)); }

// ---------------- phase A: 1440 units of (32 cols x 16 b), 3 per block (waves 0-2)
// Parity partition (r14/r15). NEW (r18): explicit weight-load pipelining —
// first granule preloaded BEFORE the staging barrier (addresses depend only on
// the unit decode), and each jt prefetches jt+1's granule before computing.
__device__ __forceinline__ void phaseA_work(const KArgs& A, float* sx, float* scr) {
  const int tid = threadIdx.x;
  const int bid = blockIdx.x;
  const int src = bid / 160;
  const int blk = bid - src * 160;  // 0..159
  const int p = blk & 1;            // shared b-half for the block's 3 units
  stage_half_coh(A.hst + ((size_t)src * BB + p * 16) * HH, sx, tid);
  const int wid = tid >> 6;
  const int lane = tid & 63;
  const int cq = lane & 7, kc = lane >> 3;
  // wave 3 aliases wave 0's unit so its (unused) preload addresses are valid
  const int u = (blk >> 1) * 6 + (wid < 3 ? wid : 0) * 2 + p;  // u&1 == p

  const float* wb; size_t wstride; size_t koff = 0;
  float* op; int opstride;
  const float* bias1 = nullptr; const float* bias2 = nullptr;
  int col0;
  if (u < 96) {  // gh (h2h for layer src), cols in [0,1536)
    int w = u >> 1; col0 = w * 32;
    wb = A.h2hT + (size_t)src * H3 * HH; wstride = HH;
    op = A.gh + (size_t)src * BB * H3; opstride = H3;
    bias1 = A.b_i2h + src * H3; bias2 = A.b_h2h + src * H3;
  } else if (u < 384) {  // ugp partial, chunk = src, q in [0,9), cols in [0,512)
    int v = u - 96; int w = v >> 1;
    int q = w >> 4; col0 = (w & 15) * 32;
    wb = A.ugT + (size_t)q * HH * H3; wstride = H3; koff = (size_t)src * HH;
    op = A.ugp + (size_t)(src * 9 + q) * BB * HH; opstride = HH;
    if (src == 0) { bias1 = A.b_wg + q * HH; bias2 = A.b_ug + q * HH; }
  } else {  // ucb, q = qi*3 + src
    int v = u - 384; int w = v >> 1;
    int qi = w >> 4; int q = qi * 3 + src; col0 = (w & 15) * 32;
    wb = A.ucT + (size_t)q * HH * HH; wstride = HH;
    op = A.ucb + (size_t)q * BB * HH; opstride = HH;
    bias1 = A.b_uc + q * HH;
  }

  const int cbase = col0 + cq * 4;
  const float* w0 = wb + (size_t)(cbase + 0) * wstride + koff;
  const float* w1 = wb + (size_t)(cbase + 1) * wstride + koff;
  const float* w2 = wb + (size_t)(cbase + 2) * wstride + koff;
  const float* w3 = wb + (size_t)(cbase + 3) * wstride + koff;

  // preload first granule — latency hides under the stage drain + barrier
  int g = kc;
  float4 va0 = *reinterpret_cast<const float4*>(w0 + (g << 2));
  float4 va1 = *reinterpret_cast<const float4*>(w1 + (g << 2));
  float4 va2 = *reinterpret_cast<const float4*>(w2 + (g << 2));
  float4 va3 = *reinterpret_cast<const float4*>(w3 + (g << 2));

  __syncthreads();
  if (wid == 3) return;  // 3 units per block; wave 3 idles past here

  const float* xb = sx;  // staged half == this block's b-rows

  float acc[4][16];
#pragma unroll
  for (int c = 0; c < 4; ++c)
#pragma unroll
    for (int b = 0; b < 16; ++b) acc[c][b] = 0.f;

  for (int jt = 0; jt < 16; ++jt) {
    const int gn = g + (jt < 15 ? 8 : 0);   // prefetch next granule (last: reload)
    float4 wn0 = *reinterpret_cast<const float4*>(w0 + (gn << 2));
    float4 wn1 = *reinterpret_cast<const float4*>(w1 + (gn << 2));
    float4 wn2 = *reinterpret_cast<const float4*>(w2 + (gn << 2));
    float4 wn3 = *reinterpret_cast<const float4*>(w3 + (gn << 2));
    const int so = xslot(g) << 2;
#pragma unroll
    for (int b = 0; b < 16; ++b) {
      float4 xv = *reinterpret_cast<const float4*>(&xb[b * HH + so]);
      acc[0][b] += dot4(xv, va0);
      acc[1][b] += dot4(xv, va1);
      acc[2][b] += dot4(xv, va2);
      acc[3][b] += dot4(xv, va3);
    }
    va0 = wn0; va1 = wn1; va2 = wn2; va3 = wn3;
    g = gn;
  }

  // reduce across the 8 kc chunks (lane bits 3..5)
#pragma unroll
  for (int c = 0; c < 4; ++c)
#pragma unroll
    for (int b = 0; b < 16; ++b) {
      float v = acc[c][b];
      v += __shfl_xor(v, 8);
      v += __shfl_xor(v, 16);
      v += __shfl_xor(v, 32);
      acc[c][b] = v;
    }

  // per-wave LDS bounce so stores use compile-time register indices
  float* wscr = scr + wid * 512;  // [cq][c][b16] = 512 floats
  if (kc == 0) {
#pragma unroll
    for (int c = 0; c < 4; ++c) {
#pragma unroll
      for (int b = 0; b < 16; b += 4) {
        *reinterpret_cast<float4*>(&wscr[cq * 64 + c * 16 + b]) =
            make_float4(acc[c][b], acc[c][b + 1], acc[c][b + 2], acc[c][b + 3]);
      }
    }
  }
  // same-wave LDS write->read; vectorized 8B coherent stores
  {
    const int bl = lane & 15;     // local b
    const int cg = lane >> 4;     // 0..3 -> 8 cols each
    const int b = p * 16 + bl;
    float* orow = op + (size_t)b * opstride + col0 + cg * 8;
#pragma unroll
    for (int i = 0; i < 8; i += 2) {
      int cl0 = cg * 8 + i, cl1 = cl0 + 1;
      float v0 = wscr[(cl0 >> 2) * 64 + (cl0 & 3) * 16 + bl];
      float v1 = wscr[(cl1 >> 2) * 64 + (cl1 & 3) * 16 + bl];
      int col = col0 + cl0;
      if (bias1) { v0 += bias1[col]; v1 += bias1[col + 1]; }
      if (bias2) { v0 += bias2[col]; v1 += bias2[col + 1]; }
      cstore2(orow + i, make_float2(v0, v1));
    }
  }
}

// ---------------- phase B: 256 units of (8 j x 8 b), unit = bid (<256).
// r17-verbatim except explicit weight-load pipelining (pre-sync preload +
// rolling prefetch, mirroring phase A).
__device__ __forceinline__ void phaseB_work(const KArgs& A, float* sx, float* scr, int l, int t) {
  const int tid = threadIdx.x;
  const int bid = blockIdx.x;
  const int jg = (bid & 7) + ((bid >> 5) << 3);  // XCD-aware 4x weight dedup (r10)
  const int bq = (bid >> 3) & 3;
  if (l == 0) stage_rows8(A.x + (size_t)t * BB * DD, sx, tid, bq * 8);
  else        stage_rows8_coh(A.hst + (size_t)(l - 1) * BB * HH, sx, tid, bq * 8);
  const int jq = tid & 7;
  const int kcl = (tid >> 3) & 7;
  const int wid = tid >> 6;
  const int j0 = jg * 8;
  const int j = j0 + jq;
  const float* w0 = A.i2hT + ((size_t)l * H3 + j) * HH;
  const float* w1 = A.i2hT + ((size_t)l * H3 + HH + j) * HH;
  const float* w2 = A.i2hT + ((size_t)l * H3 + 2 * HH + j) * HH;
  const float* w3 = A.wgT + ((size_t)(l * 3 + 0) * HH + j) * HH;
  const float* w4 = A.wgT + ((size_t)(l * 3 + 1) * HH + j) * HH;
  const float* w5 = A.wgT + ((size_t)(l * 3 + 2) * HH + j) * HH;
  const float* w6 = A.wcT + ((size_t)l * HH + j) * HH;

  // preload first granule before the barrier
  int g = (wid << 5) + kcl;
  float4 v0 = *reinterpret_cast<const float4*>(w0 + (g << 2));
  float4 v1 = *reinterpret_cast<const float4*>(w1 + (g << 2));
  float4 v2 = *reinterpret_cast<const float4*>(w2 + (g << 2));
  float4 v3 = *reinterpret_cast<const float4*>(w3 + (g << 2));
  float4 v4 = *reinterpret_cast<const float4*>(w4 + (g << 2));
  float4 v5 = *reinterpret_cast<const float4*>(w5 + (g << 2));
  float4 v6 = *reinterpret_cast<const float4*>(w6 + (g << 2));

  __syncthreads();
  const float* xb = sx + (size_t)(bq * 8) * HH;

  float acc[7][8];
#pragma unroll
  for (int m = 0; m < 7; ++m)
#pragma unroll
    for (int b = 0; b < 8; ++b) acc[m][b] = 0.f;

#pragma unroll
  for (int jt = 0; jt < 4; ++jt) {
    const int gn = g + (jt < 3 ? 8 : 0);
    float4 n0 = *reinterpret_cast<const float4*>(w0 + (gn << 2));
    float4 n1 = *reinterpret_cast<const float4*>(w1 + (gn << 2));
    float4 n2 = *reinterpret_cast<const float4*>(w2 + (gn << 2));
    float4 n3 = *reinterpret_cast<const float4*>(w3 + (gn << 2));
    float4 n4 = *reinterpret_cast<const float4*>(w4 + (gn << 2));
    float4 n5 = *reinterpret_cast<const float4*>(w5 + (gn << 2));
    float4 n6 = *reinterpret_cast<const float4*>(w6 + (gn << 2));
    const int so = xslot(g) << 2;
#pragma unroll
    for (int b = 0; b < 8; ++b) {
      float4 xv = *reinterpret_cast<const float4*>(&xb[b * HH + so]);
      acc[0][b] += dot4(xv, v0);
      acc[1][b] += dot4(xv, v1);
      acc[2][b] += dot4(xv, v2);
      acc[3][b] += dot4(xv, v3);
      acc[4][b] += dot4(xv, v4);
      acc[5][b] += dot4(xv, v5);
      acc[6][b] += dot4(xv, v6);
    }
    v0 = n0; v1 = n1; v2 = n2; v3 = n3; v4 = n4; v5 = n5; v6 = n6;
    g = gn;
  }
#pragma unroll
  for (int m = 0; m < 7; ++m)
#pragma unroll
    for (int b = 0; b < 8; ++b) {
      float v = acc[m][b];
      v += __shfl_xor(v, 8);
      v += __shfl_xor(v, 16);
      v += __shfl_xor(v, 32);
      acc[m][b] = v;
    }
  if ((tid & 63) < 8) {
    float* pp = scr + wid * 448 + jq * 56;
#pragma unroll
    for (int m = 0; m < 7; ++m) {
      *reinterpret_cast<float4*>(&pp[m * 8 + 0]) =
          make_float4(acc[m][0], acc[m][1], acc[m][2], acc[m][3]);
      *reinterpret_cast<float4*>(&pp[m * 8 + 4]) =
          make_float4(acc[m][4], acc[m][5], acc[m][6], acc[m][7]);
    }
  }
  __syncthreads();
  if (tid < 64) {
    const int jr = tid & 7, br = tid >> 3;
    float a[7];
#pragma unroll
    for (int m = 0; m < 7; ++m) {
      const int o = jr * 56 + m * 8 + br;
      a[m] = scr[o] + scr[448 + o] + scr[896 + o] + scr[1344 + o];
    }
    const int jj = j0 + jr;
    const int b = bq * 8 + br;
    const size_t bh_ = (size_t)b * HH + jj;
    const float* gh_l = A.gh + (size_t)l * BB * H3;
    float si = sigm(a[0] + cload(&gh_l[(size_t)b * H3 + jj]));
    float sf = sigm(a[1] + cload(&gh_l[(size_t)b * H3 + HH + jj]));
    float so = sigm(a[2] + cload(&gh_l[(size_t)b * H3 + 2 * HH + jj]));
    const size_t CH = 9ull * BB * HH;
    size_t o0 = ((size_t)(l * 3 + 0) * BB + b) * HH + jj;
    size_t o1 = ((size_t)(l * 3 + 1) * BB + b) * HH + jj;
    size_t o2 = ((size_t)(l * 3 + 2) * BB + b) * HH + jj;
    float g0 = sigm(a[3] + cload(&A.ugp[o0]) + cload(&A.ugp[o0 + CH]) + cload(&A.ugp[o0 + 2 * CH]));
    float g1 = sigm(a[4] + cload(&A.ugp[o1]) + cload(&A.ugp[o1 + CH]) + cload(&A.ugp[o1 + 2 * CH]));
    float g2 = sigm(a[5] + cload(&A.ugp[o2]) + cload(&A.ugp[o2 + CH]) + cload(&A.ugp[o2 + 2 * CH]));
    float accc = a[6] + A.b_wc[l * HH + jj]
               + g0 * cload(&A.ucb[o0]) + g1 * cload(&A.ucb[o1]) + g2 * cload(&A.ucb[o2]);
    float cand = tanhf(accc);
    float* cp = A.cst + (size_t)l * BB * HH + bh_;
    float* hp = A.hst + (size_t)l * BB * HH + bh_;
    float cn = sf * cload(cp) + si * cand;
    float hn = so * tanhf(cn);
    cstore(cp, cn);
    cstore(hp, hn);
    if (l == 2) A.out[(size_t)t * BB * HH + bh_] = hn;
  }
}

// ---------------- persistent cooperative kernel: whole sequence, grid 480
// Phase-specific barrier participation (r15): A-barrier 480 arrivals; B-phase
// barriers 256; idle blocks skip B0/B1 and poll only the cumulative B2 target.
__global__ __launch_bounds__(256, 2) void k_persist(KArgs A) {
  __shared__ float sx[BB * HH];
  __shared__ float scr[2048];
  unsigned int tgt = 0;
  const unsigned int nb = gridDim.x;   // 480
  for (int t = 0; t < TT; ++t) {
    phaseA_work(A, sx, scr);
    tgt += nb;
    gbar_arrive(tgt);
    for (int l = 0; l < 3; ++l) {
      tgt += 256;
      if (blockIdx.x < 256) {
        phaseB_work(A, sx, scr, l, t);
        gbar_arrive(tgt);
      } else if (l == 2) {
        gbar_wait(tgt);
      }
    }
  }
  // final states -> d_out tail (coherent reads; grid-stride)
  float* dst = A.out + (size_t)TT * BB * HH;
  for (size_t i = (size_t)blockIdx.x * 256 + threadIdx.x; i < 2 * SZ_ST;
       i += (size_t)gridDim.x * 256) {
    if (i < SZ_ST) dst[i] = cload(A.hst + i);
    else dst[i] = cload(A.cst + (i - SZ_ST));
  }
}

// fallback wrappers (non-cooperative path)
__global__ __launch_bounds__(256, 2) void k_phaseA(KArgs A) {
  __shared__ float sx[BB * HH];
  __shared__ float scr[2048];
  phaseA_work(A, sx, scr);
}
__global__ __launch_bounds__(256, 2) void k_phaseB(KArgs A, int l, int t) {
  __shared__ float sx[BB * HH];
  __shared__ float scr[2048];
  phaseB_work(A, sx, scr, l, t);
}

extern "C" void kernel_launch(void* const* d_in, const int* in_sizes, int n_in,
                              void* d_out, int out_size, void* d_ws, size_t ws_size,
                              hipStream_t stream) {
  const float* x     = (const float*)d_in[0];
  const float* h0    = (const float*)d_in[1];
  const float* c0    = (const float*)d_in[2];
  const float* W_i2h = (const float*)d_in[3];
  const float* b_i2h = (const float*)d_in[4];
  const float* W_h2h = (const float*)d_in[5];
  const float* b_h2h = (const float*)d_in[6];
  const float* W_wc  = (const float*)d_in[7];
  const float* b_wc  = (const float*)d_in[8];
  const float* W_wg  = (const float*)d_in[9];
  const float* b_wg  = (const float*)d_in[10];
  const float* W_ug  = (const float*)d_in[11];
  const float* b_ug  = (const float*)d_in[12];
  const float* W_uc  = (const float*)d_in[13];
  const float* b_uc  = (const float*)d_in[14];
  float* out = (float*)d_out;
  float* ws  = (float*)d_ws;

  if (ws_size < WS_FLOATS * sizeof(float)) return;  // need ~72.6 MB scratch

  float* i2hT = ws + OFF_I2HT;
  float* h2hT = ws + OFF_H2HT;
  float* wcT  = ws + OFF_WCT;
  float* wgT  = ws + OFF_WGT;
  float* ugT  = ws + OFF_UGT;
  float* ucT  = ws + OFF_UCT;
  float* hst  = ws + OFF_HST;
  float* cst  = ws + OFF_CST;
  float* gh   = ws + OFF_GH;
  float* ugp  = ws + OFF_UGP;
  float* ucb  = ws + OFF_UCB;

  dim3 b256(256);
  hipLaunchKernelGGL(k_transpose, dim3(48, 16, 3), b256, 0, stream, W_i2h, i2hT, 512, 1536);
  hipLaunchKernelGGL(k_transpose, dim3(48, 16, 3), b256, 0, stream, W_h2h, h2hT, 512, 1536);
  hipLaunchKernelGGL(k_transpose, dim3(16, 16, 3), b256, 0, stream, W_wc, wcT, 512, 512);
  hipLaunchKernelGGL(k_transpose, dim3(16, 16, 9), b256, 0, stream, W_wg, wgT, 512, 512);
  hipLaunchKernelGGL(k_transpose, dim3(16, 48, 9), b256, 0, stream, W_ug, ugT, 1536, 512);
  hipLaunchKernelGGL(k_transpose, dim3(16, 16, 9), b256, 0, stream, W_uc, ucT, 512, 512);
  hipLaunchKernelGGL(k_copy, dim3(192), b256, 0, stream, h0, hst, (int)SZ_ST);
  hipLaunchKernelGGL(k_copy, dim3(192), b256, 0, stream, c0, cst, (int)SZ_ST);
  hipLaunchKernelGGL(k_zero, dim3(1), dim3(256), 0, stream);

  KArgs ka;
  ka.x = x;
  ka.b_i2h = b_i2h; ka.b_h2h = b_h2h; ka.b_wg = b_wg; ka.b_ug = b_ug;
  ka.b_uc = b_uc; ka.b_wc = b_wc;
  ka.i2hT = i2hT; ka.h2hT = h2hT; ka.wcT = wcT; ka.wgT = wgT;
  ka.ugT = ugT; ka.ucT = ucT;
  ka.hst = hst; ka.cst = cst; ka.gh = gh; ka.ugp = ugp; ka.ucb = ucb;
  ka.out = out;

  void* params[1] = {&ka};
  hipError_t ce = hipLaunchCooperativeKernel((const void*)k_persist, dim3(480), dim3(256),
                                             params, 0, stream);
  if (ce != hipSuccess) {
    for (int t = 0; t < TT; ++t) {
      hipLaunchKernelGGL(k_phaseA, dim3(480), b256, 0, stream, ka);
      for (int l = 0; l < 3; ++l)
        hipLaunchKernelGGL(k_phaseB, dim3(256), b256, 0, stream, ka, l, t);
    }
    hipLaunchKernelGGL(k_copy, dim3(192), b256, 0, stream, hst,
                       out + (size_t)TT * BB * HH, (int)SZ_ST);
    hipLaunchKernelGGL(k_copy, dim3(192), b256, 0, stream, cst,
                       out + (size_t)TT * BB * HH + SZ_ST, (int)SZ_ST);
  }
}

// Round 19
// 18745.396 us; speedup vs baseline: 1.1977x; 1.1977x over previous
//
#include <hip/hip_runtime.h>
#include <math.h>

#define TT 256
#define BB 32
#define DD 512
#define HH 512
#define H3 1536

static constexpr size_t SZ_I2HT = 3ull * H3 * HH;
static constexpr size_t SZ_H2HT = 3ull * H3 * HH;
static constexpr size_t SZ_WCT  = 3ull * HH * HH;
static constexpr size_t SZ_WGT  = 9ull * HH * HH;
static constexpr size_t SZ_UGT  = 9ull * HH * H3;
static constexpr size_t SZ_UCT  = 9ull * HH * HH;
static constexpr size_t SZ_ST   = 3ull * BB * HH;
static constexpr size_t SZ_GH   = 3ull * BB * H3;
static constexpr size_t SZ_UGP  = 3ull * 9 * BB * HH;  // partials [chunk][q][b][col]
static constexpr size_t SZ_UCB  = 9ull * BB * HH;

static constexpr size_t OFF_I2HT = 0;
static constexpr size_t OFF_H2HT = OFF_I2HT + SZ_I2HT;
static constexpr size_t OFF_WCT  = OFF_H2HT + SZ_H2HT;
static constexpr size_t OFF_WGT  = OFF_WCT + SZ_WCT;
static constexpr size_t OFF_UGT  = OFF_WGT + SZ_WGT;
static constexpr size_t OFF_UCT  = OFF_UGT + SZ_UGT;
static constexpr size_t OFF_HST  = OFF_UCT + SZ_UCT;
static constexpr size_t OFF_CST  = OFF_HST + SZ_ST;
static constexpr size_t OFF_GH   = OFF_CST + SZ_ST;
static constexpr size_t OFF_UGP  = OFF_GH + SZ_GH;
static constexpr size_t OFF_UCB  = OFF_UGP + SZ_UGP;
static constexpr size_t WS_FLOATS = OFF_UCB + SZ_UCB;

struct KArgs {
  const float* x;
  const float *b_i2h, *b_h2h, *b_wg, *b_ug, *b_uc, *b_wc;
  const float *i2hT, *h2hT, *wcT, *wgT, *ugT, *ucT;
  float *hst, *cst, *gh, *ugp, *ucb, *out;
};

// ---------------- cross-XCD coherent access helpers (sc1 path, no cache flushes)
__device__ __forceinline__ float cload(const float* p) {
  return __hip_atomic_load(p, __ATOMIC_RELAXED, __HIP_MEMORY_SCOPE_AGENT);
}
__device__ __forceinline__ void cstore(float* p, float v) {
  __hip_atomic_store(p, v, __ATOMIC_RELAXED, __HIP_MEMORY_SCOPE_AGENT);
}
__device__ __forceinline__ void cstore2(float* p, float2 v) {
  __hip_atomic_store(reinterpret_cast<unsigned long long*>(p),
                     __builtin_bit_cast(unsigned long long, v),
                     __ATOMIC_RELAXED, __HIP_MEMORY_SCOPE_AGENT);
}

// ---------------- barrier: 64-sharded arrivals + wave-parallel poll (r13/r15)
__device__ unsigned int g_cnt[64 * 64];   // counters at g_cnt[i*64], 256B apart

__global__ void k_zero() {
  for (int i = threadIdx.x; i < 64 * 64; i += blockDim.x) g_cnt[i] = 0u;
}

__device__ __forceinline__ void poll_until(unsigned int target) {
  if (threadIdx.x < 64) {
    for (;;) {
      unsigned int s = __hip_atomic_load(&g_cnt[threadIdx.x * 64],
                                         __ATOMIC_RELAXED, __HIP_MEMORY_SCOPE_AGENT);
      s += __shfl_xor(s, 1);
      s += __shfl_xor(s, 2);
      s += __shfl_xor(s, 4);
      s += __shfl_xor(s, 8);
      s += __shfl_xor(s, 16);
      s += __shfl_xor(s, 32);
      if (s >= target) break;
      __builtin_amdgcn_s_sleep(8);
    }
  }
}

__device__ __forceinline__ void gbar_arrive(unsigned int target) {
  __syncthreads();
  if (threadIdx.x == 0) {
    __hip_atomic_fetch_add(&g_cnt[(blockIdx.x & 63) * 64], 1u,
                           __ATOMIC_RELAXED, __HIP_MEMORY_SCOPE_AGENT);
  }
  poll_until(target);
  __syncthreads();
}

__device__ __forceinline__ void gbar_wait(unsigned int target) {
  __syncthreads();
  poll_until(target);
  __syncthreads();
}

// ---------------- transpose: in [K][N] -> out [N][K], grid (N/32, K/32, nmat)
__global__ __launch_bounds__(256) void k_transpose(const float* __restrict__ in,
                                                   float* __restrict__ out,
                                                   int K, int N) {
  __shared__ float t[32][33];
  size_t mo = (size_t)blockIdx.z * K * N;
  in += mo; out += mo;
  int n0 = blockIdx.x * 32, k0 = blockIdx.y * 32;
  int c = threadIdx.x & 31, r0 = (threadIdx.x >> 5) * 4;
#pragma unroll
  for (int i = 0; i < 4; ++i) t[r0 + i][c] = in[(size_t)(k0 + r0 + i) * N + n0 + c];
  __syncthreads();
#pragma unroll
  for (int i = 0; i < 4; ++i) out[(size_t)(n0 + r0 + i) * K + k0 + c] = t[c][r0 + i];
}

__global__ void k_copy(const float* __restrict__ a, float* __restrict__ o, int n) {
  int i = blockIdx.x * blockDim.x + threadIdx.x;
  if (i < n) o[i] = a[i];
}

// k-aware XOR swizzle: granule g (16B) of a row stored at slot g^((g>>4)&7).
__device__ __forceinline__ int xslot(int g) { return g ^ ((g >> 4) & 7); }

// 8-row x stage for phase B l==0 (16 KB)
__device__ __forceinline__ void stage_rows8(const float* __restrict__ src,
                                            float* __restrict__ sx, int tid, int row0) {
#pragma unroll
  for (int i = 0; i < 4; ++i) {
    int fi = tid + i * 256;
    int b = row0 + (fi >> 7), g = fi & 127;
    float4 v = reinterpret_cast<const float4*>(src)[(size_t)b * 128 + g];
    *reinterpret_cast<float4*>(&sx[b * HH + (xslot(g) << 2)]) = v;
  }
}

// 8-row coherent 16B sc1 stage for phase B l>0 (r14/r17)
__device__ __forceinline__ void stage_rows8_coh(const float* __restrict__ src,
                                                float* __restrict__ sx, int tid, int row0) {
  float4 v[4];
#pragma unroll
  for (int i = 0; i < 4; ++i) {
    int fi = tid + i * 256;
    int b = row0 + (fi >> 7), g = fi & 127;
    const float* p = src + (size_t)b * HH + g * 4;
    asm volatile("global_load_dwordx4 %0, %1, off sc1" : "=v"(v[i]) : "v"(p));
  }
  asm volatile("s_waitcnt vmcnt(0)" ::: "memory");
#pragma unroll
  for (int i = 0; i < 4; ++i) {
    int fi = tid + i * 256;
    int b = row0 + (fi >> 7), g = fi & 127;
    *reinterpret_cast<float4*>(&sx[b * HH + (xslot(g) << 2)]) = v[i];
  }
}

// 16-row parity-half stage for phase A (32 KB; r14/r15)
__device__ __forceinline__ void stage_half_coh(const float* __restrict__ src,
                                               float* __restrict__ sx, int tid) {
  float4 v[8];
#pragma unroll
  for (int i = 0; i < 8; ++i) {
    int fi = tid + i * 256;
    const float* p = src + (size_t)fi * 4;
    asm volatile("global_load_dwordx4 %0, %1, off sc1" : "=v"(v[i]) : "v"(p));
  }
  asm volatile("s_waitcnt vmcnt(0)" ::: "memory");
#pragma unroll
  for (int i = 0; i < 8; ++i) {
    int fi = tid + i * 256;
    int b = fi >> 7, g = fi & 127;
    *reinterpret_cast<float4*>(&sx[b * HH + (xslot(g) << 2)]) = v[i];
  }
}

__device__ __forceinline__ float dot4(float4 x, float4 w) {
  return x.x * w.x + x.y * w.y + x.z * w.z + x.w * w.w;
}

__device__ __forceinline__ float sigm(float x) { return 1.0f / (1.0f + expf(-x)); }

// ---------------- phase A: 1440 units of (32 cols x 16 b), 3 per block (waves 0-2)
// Parity partition (r14/r15/r17-validated): all 3 units of a block share b-half
// p = blk&1. No explicit prefetch (r18 regressed — compiler schedules better).
__device__ __forceinline__ void phaseA_work(const KArgs& A, float* sx, float* scr) {
  const int tid = threadIdx.x;
  const int bid = blockIdx.x;
  const int src = bid / 160;
  const int blk = bid - src * 160;  // 0..159
  const int p = blk & 1;            // shared b-half for the block's 3 units
  stage_half_coh(A.hst + ((size_t)src * BB + p * 16) * HH, sx, tid);
  __syncthreads();
  const int wid = tid >> 6;
  if (wid == 3) return;  // 3 units per block; wave 3 idles
  const int lane = tid & 63;
  const int cq = lane & 7, kc = lane >> 3;
  const int u = (blk >> 1) * 6 + wid * 2 + p;  // 0..479 within src; u&1 == p

  const float* wb; size_t wstride; size_t koff = 0;
  float* op; int opstride;
  const float* bias1 = nullptr; const float* bias2 = nullptr;
  int col0;
  if (u < 96) {  // gh (h2h for layer src), cols in [0,1536)
    int w = u >> 1; col0 = w * 32;
    wb = A.h2hT + (size_t)src * H3 * HH; wstride = HH;
    op = A.gh + (size_t)src * BB * H3; opstride = H3;
    bias1 = A.b_i2h + src * H3; bias2 = A.b_h2h + src * H3;
  } else if (u < 384) {  // ugp partial, chunk = src, q in [0,9), cols in [0,512)
    int v = u - 96; int w = v >> 1;
    int q = w >> 4; col0 = (w & 15) * 32;
    wb = A.ugT + (size_t)q * HH * H3; wstride = H3; koff = (size_t)src * HH;
    op = A.ugp + (size_t)(src * 9 + q) * BB * HH; opstride = HH;
    if (src == 0) { bias1 = A.b_wg + q * HH; bias2 = A.b_ug + q * HH; }
  } else {  // ucb, q = qi*3 + src
    int v = u - 384; int w = v >> 1;
    int qi = w >> 4; int q = qi * 3 + src; col0 = (w & 15) * 32;
    wb = A.ucT + (size_t)q * HH * HH; wstride = HH;
    op = A.ucb + (size_t)q * BB * HH; opstride = HH;
    bias1 = A.b_uc + q * HH;
  }

  const int cbase = col0 + cq * 4;
  const float* w0 = wb + (size_t)(cbase + 0) * wstride + koff;
  const float* w1 = wb + (size_t)(cbase + 1) * wstride + koff;
  const float* w2 = wb + (size_t)(cbase + 2) * wstride + koff;
  const float* w3 = wb + (size_t)(cbase + 3) * wstride + koff;
  const float* xb = sx;  // staged half == this block's b-rows

  float acc[4][16];
#pragma unroll
  for (int c = 0; c < 4; ++c)
#pragma unroll
    for (int b = 0; b < 16; ++b) acc[c][b] = 0.f;

  for (int jt = 0; jt < 16; ++jt) {
    const int g = jt * 8 + kc;        // granule 0..127; 8 kc-lanes contiguous
    const int k = g << 2;
    float4 wv0 = *reinterpret_cast<const float4*>(w0 + k);
    float4 wv1 = *reinterpret_cast<const float4*>(w1 + k);
    float4 wv2 = *reinterpret_cast<const float4*>(w2 + k);
    float4 wv3 = *reinterpret_cast<const float4*>(w3 + k);
    const int so = xslot(g) << 2;
#pragma unroll
    for (int b = 0; b < 16; ++b) {
      float4 xv = *reinterpret_cast<const float4*>(&xb[b * HH + so]);
      acc[0][b] += dot4(xv, wv0);
      acc[1][b] += dot4(xv, wv1);
      acc[2][b] += dot4(xv, wv2);
      acc[3][b] += dot4(xv, wv3);
    }
  }

  // reduce across the 8 kc chunks (lane bits 3..5)
#pragma unroll
  for (int c = 0; c < 4; ++c)
#pragma unroll
    for (int b = 0; b < 16; ++b) {
      float v = acc[c][b];
      v += __shfl_xor(v, 8);
      v += __shfl_xor(v, 16);
      v += __shfl_xor(v, 32);
      acc[c][b] = v;
    }

  // per-wave LDS bounce so stores use compile-time register indices
  float* wscr = scr + wid * 512;  // [cq][c][b16] = 512 floats
  if (kc == 0) {
#pragma unroll
    for (int c = 0; c < 4; ++c) {
#pragma unroll
      for (int b = 0; b < 16; b += 4) {
        *reinterpret_cast<float4*>(&wscr[cq * 64 + c * 16 + b]) =
            make_float4(acc[c][b], acc[c][b + 1], acc[c][b + 2], acc[c][b + 3]);
      }
    }
  }
  // same-wave LDS write->read; vectorized 8B coherent stores
  {
    const int bl = lane & 15;     // local b
    const int cg = lane >> 4;     // 0..3 -> 8 cols each
    const int b = p * 16 + bl;
    float* orow = op + (size_t)b * opstride + col0 + cg * 8;
#pragma unroll
    for (int i = 0; i < 8; i += 2) {
      int cl0 = cg * 8 + i, cl1 = cl0 + 1;
      float v0 = wscr[(cl0 >> 2) * 64 + (cl0 & 3) * 16 + bl];
      float v1 = wscr[(cl1 >> 2) * 64 + (cl1 & 3) * 16 + bl];
      int col = col0 + cl0;
      if (bias1) { v0 += bias1[col]; v1 += bias1[col + 1]; }
      if (bias2) { v0 += bias2[col]; v1 += bias2[col + 1]; }
      cstore2(orow + i, make_float2(v0, v1));
    }
  }
}

// ---------------- phase B: 256 units of (8 j x 8 b); unit index passed in.
// r17-verbatim body; unit decode identical (jg/bq from unit), preserving the
// XCD weight-dedup property since unit%8 == bid%8 under the new bid mapping.
__device__ __forceinline__ void phaseB_work(const KArgs& A, float* sx, float* scr,
                                            int l, int t, int unit) {
  const int tid = threadIdx.x;
  const int jg = (unit & 7) + ((unit >> 5) << 3);  // invariant over bq's stride of 8
  const int bq = (unit >> 3) & 3;
  if (l == 0) stage_rows8(A.x + (size_t)t * BB * DD, sx, tid, bq * 8);
  else        stage_rows8_coh(A.hst + (size_t)(l - 1) * BB * HH, sx, tid, bq * 8);
  __syncthreads();
  const int jq = tid & 7;
  const int kcl = (tid >> 3) & 7;
  const int wid = tid >> 6;
  const int j0 = jg * 8;
  const int j = j0 + jq;
  const float* w0 = A.i2hT + ((size_t)l * H3 + j) * HH;
  const float* w1 = A.i2hT + ((size_t)l * H3 + HH + j) * HH;
  const float* w2 = A.i2hT + ((size_t)l * H3 + 2 * HH + j) * HH;
  const float* w3 = A.wgT + ((size_t)(l * 3 + 0) * HH + j) * HH;
  const float* w4 = A.wgT + ((size_t)(l * 3 + 1) * HH + j) * HH;
  const float* w5 = A.wgT + ((size_t)(l * 3 + 2) * HH + j) * HH;
  const float* w6 = A.wcT + ((size_t)l * HH + j) * HH;
  const float* xb = sx + (size_t)(bq * 8) * HH;

  float acc[7][8];
#pragma unroll
  for (int m = 0; m < 7; ++m)
#pragma unroll
    for (int b = 0; b < 8; ++b) acc[m][b] = 0.f;

  for (int jt = 0; jt < 4; ++jt) {
    const int g = wid * 32 + jt * 8 + kcl;
    const int k = g << 2;
    float4 v0 = *reinterpret_cast<const float4*>(w0 + k);
    float4 v1 = *reinterpret_cast<const float4*>(w1 + k);
    float4 v2 = *reinterpret_cast<const float4*>(w2 + k);
    float4 v3 = *reinterpret_cast<const float4*>(w3 + k);
    float4 v4 = *reinterpret_cast<const float4*>(w4 + k);
    float4 v5 = *reinterpret_cast<const float4*>(w5 + k);
    float4 v6 = *reinterpret_cast<const float4*>(w6 + k);
    const int so = xslot(g) << 2;
#pragma unroll
    for (int b = 0; b < 8; ++b) {
      float4 xv = *reinterpret_cast<const float4*>(&xb[b * HH + so]);
      acc[0][b] += dot4(xv, v0);
      acc[1][b] += dot4(xv, v1);
      acc[2][b] += dot4(xv, v2);
      acc[3][b] += dot4(xv, v3);
      acc[4][b] += dot4(xv, v4);
      acc[5][b] += dot4(xv, v5);
      acc[6][b] += dot4(xv, v6);
    }
  }
#pragma unroll
  for (int m = 0; m < 7; ++m)
#pragma unroll
    for (int b = 0; b < 8; ++b) {
      float v = acc[m][b];
      v += __shfl_xor(v, 8);
      v += __shfl_xor(v, 16);
      v += __shfl_xor(v, 32);
      acc[m][b] = v;
    }
  if ((tid & 63) < 8) {
    float* pp = scr + wid * 448 + jq * 56;
#pragma unroll
    for (int m = 0; m < 7; ++m) {
      *reinterpret_cast<float4*>(&pp[m * 8 + 0]) =
          make_float4(acc[m][0], acc[m][1], acc[m][2], acc[m][3]);
      *reinterpret_cast<float4*>(&pp[m * 8 + 4]) =
          make_float4(acc[m][4], acc[m][5], acc[m][6], acc[m][7]);
    }
  }
  __syncthreads();
  if (tid < 64) {
    const int jr = tid & 7, br = tid >> 3;
    float a[7];
#pragma unroll
    for (int m = 0; m < 7; ++m) {
      const int o = jr * 56 + m * 8 + br;
      a[m] = scr[o] + scr[448 + o] + scr[896 + o] + scr[1344 + o];
    }
    const int jj = j0 + jr;
    const int b = bq * 8 + br;
    const size_t bh_ = (size_t)b * HH + jj;
    const float* gh_l = A.gh + (size_t)l * BB * H3;
    float si = sigm(a[0] + cload(&gh_l[(size_t)b * H3 + jj]));
    float sf = sigm(a[1] + cload(&gh_l[(size_t)b * H3 + HH + jj]));
    float so = sigm(a[2] + cload(&gh_l[(size_t)b * H3 + 2 * HH + jj]));
    const size_t CH = 9ull * BB * HH;
    size_t o0 = ((size_t)(l * 3 + 0) * BB + b) * HH + jj;
    size_t o1 = ((size_t)(l * 3 + 1) * BB + b) * HH + jj;
    size_t o2 = ((size_t)(l * 3 + 2) * BB + b) * HH + jj;
    float g0 = sigm(a[3] + cload(&A.ugp[o0]) + cload(&A.ugp[o0 + CH]) + cload(&A.ugp[o0 + 2 * CH]));
    float g1 = sigm(a[4] + cload(&A.ugp[o1]) + cload(&A.ugp[o1 + CH]) + cload(&A.ugp[o1 + 2 * CH]));
    float g2 = sigm(a[5] + cload(&A.ugp[o2]) + cload(&A.ugp[o2 + CH]) + cload(&A.ugp[o2 + 2 * CH]));
    float accc = a[6] + A.b_wc[l * HH + jj]
               + g0 * cload(&A.ucb[o0]) + g1 * cload(&A.ucb[o1]) + g2 * cload(&A.ucb[o2]);
    float cand = tanhf(accc);
    float* cp = A.cst + (size_t)l * BB * HH + bh_;
    float* hp = A.hst + (size_t)l * BB * HH + bh_;
    float cn = sf * cload(cp) + si * cand;
    float hn = so * tanhf(cn);
    cstore(cp, cn);
    cstore(hp, hn);
    if (l == 2) A.out[(size_t)t * BB * HH + bh_] = hn;
  }
}

// ---------------- persistent cooperative kernel: whole sequence, grid 480
// r15 barrier participation. NEW (r19): B-active bids remapped to
// {0..127} U {256..383} so that under bid%256->CU placement, each active CU
// hosts TWO B blocks during B phases (2x waves/SIMD for latency hiding),
// instead of 256 CUs with one lonely block each. unit%8 == bid%8 preserved
// (XCD weight dedup intact); still exactly 256 B arrivals per B barrier.
__global__ __launch_bounds__(256, 2) void k_persist(KArgs A) {
  __shared__ float sx[BB * HH];
  __shared__ float scr[2048];
  const int bid = blockIdx.x;
  const bool isB = (bid < 128) || (bid >= 256 && bid < 384);
  const int bunit = (bid < 128) ? bid : (bid - 128);  // valid when isB
  unsigned int tgt = 0;
  const unsigned int nb = gridDim.x;   // 480
  for (int t = 0; t < TT; ++t) {
    phaseA_work(A, sx, scr);
    tgt += nb;
    gbar_arrive(tgt);
    for (int l = 0; l < 3; ++l) {
      tgt += 256;
      if (isB) {
        phaseB_work(A, sx, scr, l, t, bunit);
        gbar_arrive(tgt);
      } else if (l == 2) {
        gbar_wait(tgt);
      }
    }
  }
  // final states -> d_out tail (coherent reads; grid-stride)
  float* dst = A.out + (size_t)TT * BB * HH;
  for (size_t i = (size_t)blockIdx.x * 256 + threadIdx.x; i < 2 * SZ_ST;
       i += (size_t)gridDim.x * 256) {
    if (i < SZ_ST) dst[i] = cload(A.hst + i);
    else dst[i] = cload(A.cst + (i - SZ_ST));
  }
}

// fallback wrappers (non-cooperative path)
__global__ __launch_bounds__(256, 2) void k_phaseA(KArgs A) {
  __shared__ float sx[BB * HH];
  __shared__ float scr[2048];
  phaseA_work(A, sx, scr);
}
__global__ __launch_bounds__(256, 2) void k_phaseB(KArgs A, int l, int t) {
  __shared__ float sx[BB * HH];
  __shared__ float scr[2048];
  phaseB_work(A, sx, scr, l, t, blockIdx.x);
}

extern "C" void kernel_launch(void* const* d_in, const int* in_sizes, int n_in,
                              void* d_out, int out_size, void* d_ws, size_t ws_size,
                              hipStream_t stream) {
  const float* x     = (const float*)d_in[0];
  const float* h0    = (const float*)d_in[1];
  const float* c0    = (const float*)d_in[2];
  const float* W_i2h = (const float*)d_in[3];
  const float* b_i2h = (const float*)d_in[4];
  const float* W_h2h = (const float*)d_in[5];
  const float* b_h2h = (const float*)d_in[6];
  const float* W_wc  = (const float*)d_in[7];
  const float* b_wc  = (const float*)d_in[8];
  const float* W_wg  = (const float*)d_in[9];
  const float* b_wg  = (const float*)d_in[10];
  const float* W_ug  = (const float*)d_in[11];
  const float* b_ug  = (const float*)d_in[12];
  const float* W_uc  = (const float*)d_in[13];
  const float* b_uc  = (const float*)d_in[14];
  float* out = (float*)d_out;
  float* ws  = (float*)d_ws;

  if (ws_size < WS_FLOATS * sizeof(float)) return;  // need ~72.6 MB scratch

  float* i2hT = ws + OFF_I2HT;
  float* h2hT = ws + OFF_H2HT;
  float* wcT  = ws + OFF_WCT;
  float* wgT  = ws + OFF_WGT;
  float* ugT  = ws + OFF_UGT;
  float* ucT  = ws + OFF_UCT;
  float* hst  = ws + OFF_HST;
  float* cst  = ws + OFF_CST;
  float* gh   = ws + OFF_GH;
  float* ugp  = ws + OFF_UGP;
  float* ucb  = ws + OFF_UCB;

  dim3 b256(256);
  hipLaunchKernelGGL(k_transpose, dim3(48, 16, 3), b256, 0, stream, W_i2h, i2hT, 512, 1536);
  hipLaunchKernelGGL(k_transpose, dim3(48, 16, 3), b256, 0, stream, W_h2h, h2hT, 512, 1536);
  hipLaunchKernelGGL(k_transpose, dim3(16, 16, 3), b256, 0, stream, W_wc, wcT, 512, 512);
  hipLaunchKernelGGL(k_transpose, dim3(16, 16, 9), b256, 0, stream, W_wg, wgT, 512, 512);
  hipLaunchKernelGGL(k_transpose, dim3(16, 48, 9), b256, 0, stream, W_ug, ugT, 1536, 512);
  hipLaunchKernelGGL(k_transpose, dim3(16, 16, 9), b256, 0, stream, W_uc, ucT, 512, 512);
  hipLaunchKernelGGL(k_copy, dim3(192), b256, 0, stream, h0, hst, (int)SZ_ST);
  hipLaunchKernelGGL(k_copy, dim3(192), b256, 0, stream, c0, cst, (int)SZ_ST);
  hipLaunchKernelGGL(k_zero, dim3(1), dim3(256), 0, stream);

  KArgs ka;
  ka.x = x;
  ka.b_i2h = b_i2h; ka.b_h2h = b_h2h; ka.b_wg = b_wg; ka.b_ug = b_ug;
  ka.b_uc = b_uc; ka.b_wc = b_wc;
  ka.i2hT = i2hT; ka.h2hT = h2hT; ka.wcT = wcT; ka.wgT = wgT;
  ka.ugT = ugT; ka.ucT = ucT;
  ka.hst = hst; ka.cst = cst; ka.gh = gh; ka.ugp = ugp; ka.ucb = ucb;
  ka.out = out;

  void* params[1] = {&ka};
  hipError_t ce = hipLaunchCooperativeKernel((const void*)k_persist, dim3(480), dim3(256),
                                             params, 0, stream);
  if (ce != hipSuccess) {
    for (int t = 0; t < TT; ++t) {
      hipLaunchKernelGGL(k_phaseA, dim3(480), b256, 0, stream, ka);
      for (int l = 0; l < 3; ++l)
        hipLaunchKernelGGL(k_phaseB, dim3(256), b256, 0, stream, ka, l, t);
    }
    hipLaunchKernelGGL(k_copy, dim3(192), b256, 0, stream, hst,
                       out + (size_t)TT * BB * HH, (int)SZ_ST);
    hipLaunchKernelGGL(k_copy, dim3(192), b256, 0, stream, cst,
                       out + (size_t)TT * BB * HH + SZ_ST, (int)SZ_ST);
  }
}

// Round 20
// 15950.616 us; speedup vs baseline: 1.4076x; 1.1752x over previous
//
#include <hip/hip_runtime.h>
#include <math.h>

#define TT 256
#define BB 32
#define DD 512
#define HH 512
#define H3 1536

static constexpr size_t SZ_I2HT = 3ull * H3 * HH;
static constexpr size_t SZ_H2HT = 3ull * H3 * HH;
static constexpr size_t SZ_WCT  = 3ull * HH * HH;
static constexpr size_t SZ_WGT  = 9ull * HH * HH;
static constexpr size_t SZ_UGT  = 9ull * HH * H3;
static constexpr size_t SZ_UCT  = 9ull * HH * HH;
static constexpr size_t SZ_ST   = 3ull * BB * HH;
static constexpr size_t SZ_GH   = 3ull * BB * H3;
static constexpr size_t SZ_UGP  = 3ull * 9 * BB * HH;  // partials [chunk][q][b][col]
static constexpr size_t SZ_UCB  = 9ull * BB * HH;

static constexpr size_t OFF_I2HT = 0;
static constexpr size_t OFF_H2HT = OFF_I2HT + SZ_I2HT;
static constexpr size_t OFF_WCT  = OFF_H2HT + SZ_H2HT;
static constexpr size_t OFF_WGT  = OFF_WCT + SZ_WCT;
static constexpr size_t OFF_UGT  = OFF_WGT + SZ_WGT;
static constexpr size_t OFF_UCT  = OFF_UGT + SZ_UGT;
static constexpr size_t OFF_HST  = OFF_UCT + SZ_UCT;
static constexpr size_t OFF_CST  = OFF_HST + SZ_ST;
static constexpr size_t OFF_GH   = OFF_CST + SZ_ST;
static constexpr size_t OFF_UGP  = OFF_GH + SZ_GH;
static constexpr size_t OFF_UCB  = OFF_UGP + SZ_UGP;
static constexpr size_t WS_FLOATS = OFF_UCB + SZ_UCB;

struct KArgs {
  const float* x;
  const float *b_i2h, *b_h2h, *b_wg, *b_ug, *b_uc, *b_wc;
  const float *i2hT, *h2hT, *wcT, *wgT, *ugT, *ucT;
  float *hst, *cst, *gh, *ugp, *ucb, *out;
};

// ---------------- cross-XCD coherent access helpers (sc1 path, no cache flushes)
__device__ __forceinline__ float cload(const float* p) {
  return __hip_atomic_load(p, __ATOMIC_RELAXED, __HIP_MEMORY_SCOPE_AGENT);
}
__device__ __forceinline__ void cstore(float* p, float v) {
  __hip_atomic_store(p, v, __ATOMIC_RELAXED, __HIP_MEMORY_SCOPE_AGENT);
}
__device__ __forceinline__ void cstore2(float* p, float2 v) {
  __hip_atomic_store(reinterpret_cast<unsigned long long*>(p),
                     __builtin_bit_cast(unsigned long long, v),
                     __ATOMIC_RELAXED, __HIP_MEMORY_SCOPE_AGENT);
}

// ---------------- barrier: 64-sharded arrivals + wave-parallel poll (r13/r15)
__device__ unsigned int g_cnt[64 * 64];   // counters at g_cnt[i*64], 256B apart

__global__ void k_zero() {
  for (int i = threadIdx.x; i < 64 * 64; i += blockDim.x) g_cnt[i] = 0u;
}

__device__ __forceinline__ void poll_until(unsigned int target) {
  if (threadIdx.x < 64) {
    for (;;) {
      unsigned int s = __hip_atomic_load(&g_cnt[threadIdx.x * 64],
                                         __ATOMIC_RELAXED, __HIP_MEMORY_SCOPE_AGENT);
      s += __shfl_xor(s, 1);
      s += __shfl_xor(s, 2);
      s += __shfl_xor(s, 4);
      s += __shfl_xor(s, 8);
      s += __shfl_xor(s, 16);
      s += __shfl_xor(s, 32);
      if (s >= target) break;
      __builtin_amdgcn_s_sleep(8);
    }
  }
}

__device__ __forceinline__ void gbar_arrive(unsigned int target) {
  __syncthreads();
  if (threadIdx.x == 0) {
    __hip_atomic_fetch_add(&g_cnt[(blockIdx.x & 63) * 64], 1u,
                           __ATOMIC_RELAXED, __HIP_MEMORY_SCOPE_AGENT);
  }
  poll_until(target);
  __syncthreads();
}

__device__ __forceinline__ void gbar_wait(unsigned int target) {
  __syncthreads();
  poll_until(target);
  __syncthreads();
}

// ---------------- transpose: in [K][N] -> out [N][K], grid (N/32, K/32, nmat)
__global__ __launch_bounds__(256) void k_transpose(const float* __restrict__ in,
                                                   float* __restrict__ out,
                                                   int K, int N) {
  __shared__ float t[32][33];
  size_t mo = (size_t)blockIdx.z * K * N;
  in += mo; out += mo;
  int n0 = blockIdx.x * 32, k0 = blockIdx.y * 32;
  int c = threadIdx.x & 31, r0 = (threadIdx.x >> 5) * 4;
#pragma unroll
  for (int i = 0; i < 4; ++i) t[r0 + i][c] = in[(size_t)(k0 + r0 + i) * N + n0 + c];
  __syncthreads();
#pragma unroll
  for (int i = 0; i < 4; ++i) out[(size_t)(n0 + r0 + i) * K + k0 + c] = t[c][r0 + i];
}

__global__ void k_copy(const float* __restrict__ a, float* __restrict__ o, int n) {
  int i = blockIdx.x * blockDim.x + threadIdx.x;
  if (i < n) o[i] = a[i];
}

// k-aware XOR swizzle: granule g (16B) of a row stored at slot g^((g>>4)&7).
__device__ __forceinline__ int xslot(int g) { return g ^ ((g >> 4) & 7); }

// 8-row x stage for phase B l==0 (16 KB)
__device__ __forceinline__ void stage_rows8(const float* __restrict__ src,
                                            float* __restrict__ sx, int tid, int row0) {
#pragma unroll
  for (int i = 0; i < 4; ++i) {
    int fi = tid + i * 256;
    int b = row0 + (fi >> 7), g = fi & 127;
    float4 v = reinterpret_cast<const float4*>(src)[(size_t)b * 128 + g];
    *reinterpret_cast<float4*>(&sx[b * HH + (xslot(g) << 2)]) = v;
  }
}

// 8-row coherent 16B sc1 stage for phase B l>0 (r14/r17)
__device__ __forceinline__ void stage_rows8_coh(const float* __restrict__ src,
                                                float* __restrict__ sx, int tid, int row0) {
  float4 v[4];
#pragma unroll
  for (int i = 0; i < 4; ++i) {
    int fi = tid + i * 256;
    int b = row0 + (fi >> 7), g = fi & 127;
    const float* p = src + (size_t)b * HH + g * 4;
    asm volatile("global_load_dwordx4 %0, %1, off sc1" : "=v"(v[i]) : "v"(p));
  }
  asm volatile("s_waitcnt vmcnt(0)" ::: "memory");
#pragma unroll
  for (int i = 0; i < 4; ++i) {
    int fi = tid + i * 256;
    int b = row0 + (fi >> 7), g = fi & 127;
    *reinterpret_cast<float4*>(&sx[b * HH + (xslot(g) << 2)]) = v[i];
  }
}

// 16-row parity-half stage for phase A (32 KB; r14/r15)
__device__ __forceinline__ void stage_half_coh(const float* __restrict__ src,
                                               float* __restrict__ sx, int tid) {
  float4 v[8];
#pragma unroll
  for (int i = 0; i < 8; ++i) {
    int fi = tid + i * 256;
    const float* p = src + (size_t)fi * 4;
    asm volatile("global_load_dwordx4 %0, %1, off sc1" : "=v"(v[i]) : "v"(p));
  }
  asm volatile("s_waitcnt vmcnt(0)" ::: "memory");
#pragma unroll
  for (int i = 0; i < 8; ++i) {
    int fi = tid + i * 256;
    int b = fi >> 7, g = fi & 127;
    *reinterpret_cast<float4*>(&sx[b * HH + (xslot(g) << 2)]) = v[i];
  }
}

__device__ __forceinline__ float dot4(float4 x, float4 w) {
  return x.x * w.x + x.y * w.y + x.z * w.z + x.w * w.w;
}

__device__ __forceinline__ float sigm(float x) { return 1.0f / (1.0f + expf(-x)); }

// ---------------- phase A: 1440 units of (32 cols x 16 b), 3 per block (waves 0-2)
// Parity partition (r14/r15/r17-validated): all 3 units of a block share b-half
// p = blk&1, so only 16 rows of h[src] are staged (32 KB).
__device__ __forceinline__ void phaseA_work(const KArgs& A, float* sx, float* scr) {
  const int tid = threadIdx.x;
  const int bid = blockIdx.x;
  const int src = bid / 160;
  const int blk = bid - src * 160;  // 0..159
  const int p = blk & 1;            // shared b-half for the block's 3 units
  stage_half_coh(A.hst + ((size_t)src * BB + p * 16) * HH, sx, tid);
  __syncthreads();
  const int wid = tid >> 6;
  if (wid == 3) return;  // 3 units per block; wave 3 idles
  const int lane = tid & 63;
  const int cq = lane & 7, kc = lane >> 3;
  const int u = (blk >> 1) * 6 + wid * 2 + p;  // 0..479 within src; u&1 == p

  const float* wb; size_t wstride; size_t koff = 0;
  float* op; int opstride;
  const float* bias1 = nullptr; const float* bias2 = nullptr;
  int col0;
  if (u < 96) {  // gh (h2h for layer src), cols in [0,1536)
    int w = u >> 1; col0 = w * 32;
    wb = A.h2hT + (size_t)src * H3 * HH; wstride = HH;
    op = A.gh + (size_t)src * BB * H3; opstride = H3;
    bias1 = A.b_i2h + src * H3; bias2 = A.b_h2h + src * H3;
  } else if (u < 384) {  // ugp partial, chunk = src, q in [0,9), cols in [0,512)
    int v = u - 96; int w = v >> 1;
    int q = w >> 4; col0 = (w & 15) * 32;
    wb = A.ugT + (size_t)q * HH * H3; wstride = H3; koff = (size_t)src * HH;
    op = A.ugp + (size_t)(src * 9 + q) * BB * HH; opstride = HH;
    if (src == 0) { bias1 = A.b_wg + q * HH; bias2 = A.b_ug + q * HH; }
  } else {  // ucb, q = qi*3 + src
    int v = u - 384; int w = v >> 1;
    int qi = w >> 4; int q = qi * 3 + src; col0 = (w & 15) * 32;
    wb = A.ucT + (size_t)q * HH * HH; wstride = HH;
    op = A.ucb + (size_t)q * BB * HH; opstride = HH;
    bias1 = A.b_uc + q * HH;
  }

  const int cbase = col0 + cq * 4;
  const float* w0 = wb + (size_t)(cbase + 0) * wstride + koff;
  const float* w1 = wb + (size_t)(cbase + 1) * wstride + koff;
  const float* w2 = wb + (size_t)(cbase + 2) * wstride + koff;
  const float* w3 = wb + (size_t)(cbase + 3) * wstride + koff;
  const float* xb = sx;  // staged half == this block's b-rows

  float acc[4][16];
#pragma unroll
  for (int c = 0; c < 4; ++c)
#pragma unroll
    for (int b = 0; b < 16; ++b) acc[c][b] = 0.f;

  for (int jt = 0; jt < 16; ++jt) {
    const int g = jt * 8 + kc;        // granule 0..127; 8 kc-lanes contiguous
    const int k = g << 2;
    float4 wv0 = *reinterpret_cast<const float4*>(w0 + k);
    float4 wv1 = *reinterpret_cast<const float4*>(w1 + k);
    float4 wv2 = *reinterpret_cast<const float4*>(w2 + k);
    float4 wv3 = *reinterpret_cast<const float4*>(w3 + k);
    const int so = xslot(g) << 2;
#pragma unroll
    for (int b = 0; b < 16; ++b) {
      float4 xv = *reinterpret_cast<const float4*>(&xb[b * HH + so]);
      acc[0][b] += dot4(xv, wv0);
      acc[1][b] += dot4(xv, wv1);
      acc[2][b] += dot4(xv, wv2);
      acc[3][b] += dot4(xv, wv3);
    }
  }

  // reduce across the 8 kc chunks (lane bits 3..5)
#pragma unroll
  for (int c = 0; c < 4; ++c)
#pragma unroll
    for (int b = 0; b < 16; ++b) {
      float v = acc[c][b];
      v += __shfl_xor(v, 8);
      v += __shfl_xor(v, 16);
      v += __shfl_xor(v, 32);
      acc[c][b] = v;
    }

  // per-wave LDS bounce so stores use compile-time register indices
  float* wscr = scr + wid * 512;  // [cq][c][b16] = 512 floats
  if (kc == 0) {
#pragma unroll
    for (int c = 0; c < 4; ++c) {
#pragma unroll
      for (int b = 0; b < 16; b += 4) {
        *reinterpret_cast<float4*>(&wscr[cq * 64 + c * 16 + b]) =
            make_float4(acc[c][b], acc[c][b + 1], acc[c][b + 2], acc[c][b + 3]);
      }
    }
  }
  // same-wave LDS write->read; vectorized 8B coherent stores
  {
    const int bl = lane & 15;     // local b
    const int cg = lane >> 4;     // 0..3 -> 8 cols each
    const int b = p * 16 + bl;
    float* orow = op + (size_t)b * opstride + col0 + cg * 8;
#pragma unroll
    for (int i = 0; i < 8; i += 2) {
      int cl0 = cg * 8 + i, cl1 = cl0 + 1;
      float v0 = wscr[(cl0 >> 2) * 64 + (cl0 & 3) * 16 + bl];
      float v1 = wscr[(cl1 >> 2) * 64 + (cl1 & 3) * 16 + bl];
      int col = col0 + cl0;
      if (bias1) { v0 += bias1[col]; v1 += bias1[col + 1]; }
      if (bias2) { v0 += bias2[col]; v1 += bias2[col + 1]; }
      cstore2(orow + i, make_float2(v0, v1));
    }
  }
}

// ---------------- phase B: 256 units of (8 j x 8 b), unit = bid (<256).
// r17-verbatim: 8-row staging (16 KB), XCD-aware weight dedup mapping (r10).
__device__ __forceinline__ void phaseB_work(const KArgs& A, float* sx, float* scr, int l, int t) {
  const int tid = threadIdx.x;
  const int bid = blockIdx.x;
  const int jg = (bid & 7) + ((bid >> 5) << 3);  // invariant over bq's bid stride of 8
  const int bq = (bid >> 3) & 3;
  if (l == 0) stage_rows8(A.x + (size_t)t * BB * DD, sx, tid, bq * 8);
  else        stage_rows8_coh(A.hst + (size_t)(l - 1) * BB * HH, sx, tid, bq * 8);
  __syncthreads();
  const int jq = tid & 7;
  const int kcl = (tid >> 3) & 7;
  const int wid = tid >> 6;
  const int j0 = jg * 8;
  const int j = j0 + jq;
  const float* w0 = A.i2hT + ((size_t)l * H3 + j) * HH;
  const float* w1 = A.i2hT + ((size_t)l * H3 + HH + j) * HH;
  const float* w2 = A.i2hT + ((size_t)l * H3 + 2 * HH + j) * HH;
  const float* w3 = A.wgT + ((size_t)(l * 3 + 0) * HH + j) * HH;
  const float* w4 = A.wgT + ((size_t)(l * 3 + 1) * HH + j) * HH;
  const float* w5 = A.wgT + ((size_t)(l * 3 + 2) * HH + j) * HH;
  const float* w6 = A.wcT + ((size_t)l * HH + j) * HH;
  const float* xb = sx + (size_t)(bq * 8) * HH;

  float acc[7][8];
#pragma unroll
  for (int m = 0; m < 7; ++m)
#pragma unroll
    for (int b = 0; b < 8; ++b) acc[m][b] = 0.f;

  for (int jt = 0; jt < 4; ++jt) {
    const int g = wid * 32 + jt * 8 + kcl;
    const int k = g << 2;
    float4 v0 = *reinterpret_cast<const float4*>(w0 + k);
    float4 v1 = *reinterpret_cast<const float4*>(w1 + k);
    float4 v2 = *reinterpret_cast<const float4*>(w2 + k);
    float4 v3 = *reinterpret_cast<const float4*>(w3 + k);
    float4 v4 = *reinterpret_cast<const float4*>(w4 + k);
    float4 v5 = *reinterpret_cast<const float4*>(w5 + k);
    float4 v6 = *reinterpret_cast<const float4*>(w6 + k);
    const int so = xslot(g) << 2;
#pragma unroll
    for (int b = 0; b < 8; ++b) {
      float4 xv = *reinterpret_cast<const float4*>(&xb[b * HH + so]);
      acc[0][b] += dot4(xv, v0);
      acc[1][b] += dot4(xv, v1);
      acc[2][b] += dot4(xv, v2);
      acc[3][b] += dot4(xv, v3);
      acc[4][b] += dot4(xv, v4);
      acc[5][b] += dot4(xv, v5);
      acc[6][b] += dot4(xv, v6);
    }
  }
#pragma unroll
  for (int m = 0; m < 7; ++m)
#pragma unroll
    for (int b = 0; b < 8; ++b) {
      float v = acc[m][b];
      v += __shfl_xor(v, 8);
      v += __shfl_xor(v, 16);
      v += __shfl_xor(v, 32);
      acc[m][b] = v;
    }
  if ((tid & 63) < 8) {
    float* pp = scr + wid * 448 + jq * 56;
#pragma unroll
    for (int m = 0; m < 7; ++m) {
      *reinterpret_cast<float4*>(&pp[m * 8 + 0]) =
          make_float4(acc[m][0], acc[m][1], acc[m][2], acc[m][3]);
      *reinterpret_cast<float4*>(&pp[m * 8 + 4]) =
          make_float4(acc[m][4], acc[m][5], acc[m][6], acc[m][7]);
    }
  }
  __syncthreads();
  if (tid < 64) {
    const int jr = tid & 7, br = tid >> 3;
    float a[7];
#pragma unroll
    for (int m = 0; m < 7; ++m) {
      const int o = jr * 56 + m * 8 + br;
      a[m] = scr[o] + scr[448 + o] + scr[896 + o] + scr[1344 + o];
    }
    const int jj = j0 + jr;
    const int b = bq * 8 + br;
    const size_t bh_ = (size_t)b * HH + jj;
    const float* gh_l = A.gh + (size_t)l * BB * H3;
    float si = sigm(a[0] + cload(&gh_l[(size_t)b * H3 + jj]));
    float sf = sigm(a[1] + cload(&gh_l[(size_t)b * H3 + HH + jj]));
    float so = sigm(a[2] + cload(&gh_l[(size_t)b * H3 + 2 * HH + jj]));
    const size_t CH = 9ull * BB * HH;
    size_t o0 = ((size_t)(l * 3 + 0) * BB + b) * HH + jj;
    size_t o1 = ((size_t)(l * 3 + 1) * BB + b) * HH + jj;
    size_t o2 = ((size_t)(l * 3 + 2) * BB + b) * HH + jj;
    float g0 = sigm(a[3] + cload(&A.ugp[o0]) + cload(&A.ugp[o0 + CH]) + cload(&A.ugp[o0 + 2 * CH]));
    float g1 = sigm(a[4] + cload(&A.ugp[o1]) + cload(&A.ugp[o1 + CH]) + cload(&A.ugp[o1 + 2 * CH]));
    float g2 = sigm(a[5] + cload(&A.ugp[o2]) + cload(&A.ugp[o2 + CH]) + cload(&A.ugp[o2 + 2 * CH]));
    float accc = a[6] + A.b_wc[l * HH + jj]
               + g0 * cload(&A.ucb[o0]) + g1 * cload(&A.ucb[o1]) + g2 * cload(&A.ucb[o2]);
    float cand = tanhf(accc);
    float* cp = A.cst + (size_t)l * BB * HH + bh_;
    float* hp = A.hst + (size_t)l * BB * HH + bh_;
    float cn = sf * cload(cp) + si * cand;
    float hn = so * tanhf(cn);
    cstore(cp, cn);
    cstore(hp, hn);
    if (l == 2) A.out[(size_t)t * BB * HH + bh_] = hn;
  }
}

// ---------------- persistent cooperative kernel: whole sequence, grid 480
// Phase-specific barrier participation (r15): A-barrier 480 arrivals; B-phase
// barriers 256; idle blocks skip B0/B1 and poll only the cumulative B2 target.
__global__ __launch_bounds__(256, 2) void k_persist(KArgs A) {
  __shared__ float sx[BB * HH];
  __shared__ float scr[2048];
  unsigned int tgt = 0;
  const unsigned int nb = gridDim.x;   // 480
  for (int t = 0; t < TT; ++t) {
    phaseA_work(A, sx, scr);
    tgt += nb;
    gbar_arrive(tgt);
    for (int l = 0; l < 3; ++l) {
      tgt += 256;
      if (blockIdx.x < 256) {
        phaseB_work(A, sx, scr, l, t);
        gbar_arrive(tgt);
      } else if (l == 2) {
        gbar_wait(tgt);
      }
    }
  }
  // final states -> d_out tail (coherent reads; grid-stride)
  float* dst = A.out + (size_t)TT * BB * HH;
  for (size_t i = (size_t)blockIdx.x * 256 + threadIdx.x; i < 2 * SZ_ST;
       i += (size_t)gridDim.x * 256) {
    if (i < SZ_ST) dst[i] = cload(A.hst + i);
    else dst[i] = cload(A.cst + (i - SZ_ST));
  }
}

// fallback wrappers (non-cooperative path)
__global__ __launch_bounds__(256, 2) void k_phaseA(KArgs A) {
  __shared__ float sx[BB * HH];
  __shared__ float scr[2048];
  phaseA_work(A, sx, scr);
}
__global__ __launch_bounds__(256, 2) void k_phaseB(KArgs A, int l, int t) {
  __shared__ float sx[BB * HH];
  __shared__ float scr[2048];
  phaseB_work(A, sx, scr, l, t);
}

extern "C" void kernel_launch(void* const* d_in, const int* in_sizes, int n_in,
                              void* d_out, int out_size, void* d_ws, size_t ws_size,
                              hipStream_t stream) {
  const float* x     = (const float*)d_in[0];
  const float* h0    = (const float*)d_in[1];
  const float* c0    = (const float*)d_in[2];
  const float* W_i2h = (const float*)d_in[3];
  const float* b_i2h = (const float*)d_in[4];
  const float* W_h2h = (const float*)d_in[5];
  const float* b_h2h = (const float*)d_in[6];
  const float* W_wc  = (const float*)d_in[7];
  const float* b_wc  = (const float*)d_in[8];
  const float* W_wg  = (const float*)d_in[9];
  const float* b_wg  = (const float*)d_in[10];
  const float* W_ug  = (const float*)d_in[11];
  const float* b_ug  = (const float*)d_in[12];
  const float* W_uc  = (const float*)d_in[13];
  const float* b_uc  = (const float*)d_in[14];
  float* out = (float*)d_out;
  float* ws  = (float*)d_ws;

  if (ws_size < WS_FLOATS * sizeof(float)) return;  // need ~72.6 MB scratch

  float* i2hT = ws + OFF_I2HT;
  float* h2hT = ws + OFF_H2HT;
  float* wcT  = ws + OFF_WCT;
  float* wgT  = ws + OFF_WGT;
  float* ugT  = ws + OFF_UGT;
  float* ucT  = ws + OFF_UCT;
  float* hst  = ws + OFF_HST;
  float* cst  = ws + OFF_CST;
  float* gh   = ws + OFF_GH;
  float* ugp  = ws + OFF_UGP;
  float* ucb  = ws + OFF_UCB;

  dim3 b256(256);
  hipLaunchKernelGGL(k_transpose, dim3(48, 16, 3), b256, 0, stream, W_i2h, i2hT, 512, 1536);
  hipLaunchKernelGGL(k_transpose, dim3(48, 16, 3), b256, 0, stream, W_h2h, h2hT, 512, 1536);
  hipLaunchKernelGGL(k_transpose, dim3(16, 16, 3), b256, 0, stream, W_wc, wcT, 512, 512);
  hipLaunchKernelGGL(k_transpose, dim3(16, 16, 9), b256, 0, stream, W_wg, wgT, 512, 512);
  hipLaunchKernelGGL(k_transpose, dim3(16, 48, 9), b256, 0, stream, W_ug, ugT, 1536, 512);
  hipLaunchKernelGGL(k_transpose, dim3(16, 16, 9), b256, 0, stream, W_uc, ucT, 512, 512);
  hipLaunchKernelGGL(k_copy, dim3(192), b256, 0, stream, h0, hst, (int)SZ_ST);
  hipLaunchKernelGGL(k_copy, dim3(192), b256, 0, stream, c0, cst, (int)SZ_ST);
  hipLaunchKernelGGL(k_zero, dim3(1), dim3(256), 0, stream);

  KArgs ka;
  ka.x = x;
  ka.b_i2h = b_i2h; ka.b_h2h = b_h2h; ka.b_wg = b_wg; ka.b_ug = b_ug;
  ka.b_uc = b_uc; ka.b_wc = b_wc;
  ka.i2hT = i2hT; ka.h2hT = h2hT; ka.wcT = wcT; ka.wgT = wgT;
  ka.ugT = ugT; ka.ucT = ucT;
  ka.hst = hst; ka.cst = cst; ka.gh = gh; ka.ugp = ugp; ka.ucb = ucb;
  ka.out = out;

  void* params[1] = {&ka};
  hipError_t ce = hipLaunchCooperativeKernel((const void*)k_persist, dim3(480), dim3(256),
                                             params, 0, stream);
  if (ce != hipSuccess) {
    for (int t = 0; t < TT; ++t) {
      hipLaunchKernelGGL(k_phaseA, dim3(480), b256, 0, stream, ka);
      for (int l = 0; l < 3; ++l)
        hipLaunchKernelGGL(k_phaseB, dim3(256), b256, 0, stream, ka, l, t);
    }
    hipLaunchKernelGGL(k_copy, dim3(192), b256, 0, stream, hst,
                       out + (size_t)TT * BB * HH, (int)SZ_ST);
    hipLaunchKernelGGL(k_copy, dim3(192), b256, 0, stream, cst,
                       out + (size_t)TT * BB * HH + SZ_ST, (int)SZ_ST);
  }
}